// Round 3
// baseline (639.133 us; speedup 1.0000x reference)
//
#include <hip/hip_runtime.h>
#include <math.h>

#define B_    2048
#define N_    36
#define EMB_  1024
#define SIMD_ 16
#define HID_  32
#define K_    8
#define NROW  (B_ * N_)   // 73728

// Proved in R1 (absmax 0.0): Gaussian-kernel graph weights row-normalize to
// S/(S+1e-8) ~= 1 and node features are j-independent -> pairwise pipeline
// folds to identity; gk_mean/gk_prec irrelevant at the 1.55e-3 tolerance.
//
// ws layout (floats):
//   [0,512)     WsumT[h][d] = sum_k gcn_w[k][d][h]   (TRANSPOSED: rows contiguous per h)
//   [512,1536)  W1[h][j]    (weight-normed out1, row-major)
//   [1536,1568) b1
//   [1568,1600) w2 (weight-normed out2 row)
//   [1600]      b2
__global__ __launch_bounds__(64) void fold_weights(
    const float* __restrict__ gcn_w,
    const float* __restrict__ out1_v, const float* __restrict__ out1_g,
    const float* __restrict__ out1_b,
    const float* __restrict__ out2_v, const float* __restrict__ out2_g,
    const float* __restrict__ out2_b,
    float* __restrict__ wsf)
{
    const int t = threadIdx.x;
    for (int idx = t; idx < SIMD_ * HID_; idx += 64) {
        const int h = idx >> 4, d = idx & 15;
        float s = 0.f;
        #pragma unroll
        for (int k = 0; k < K_; ++k) s += gcn_w[k * SIMD_ * HID_ + d * HID_ + h];
        wsf[idx] = s;                      // WsumT[h][d]
    }
    if (t < HID_) {
        float nrm = 0.f;
        #pragma unroll
        for (int j = 0; j < HID_; ++j) { float v = out1_v[t * HID_ + j]; nrm += v * v; }
        float sc = out1_g[t] / (sqrtf(nrm) + 1e-12f);
        #pragma unroll
        for (int j = 0; j < HID_; ++j) wsf[512 + t * HID_ + j] = out1_v[t * HID_ + j] * sc;
        wsf[1536 + t] = out1_b[t];
        float n2 = 0.f;
        #pragma unroll
        for (int j = 0; j < HID_; ++j) { float v = out2_v[j]; n2 += v * v; }
        wsf[1568 + t] = out2_g[0] * out2_v[t] / (sqrtf(n2) + 1e-12f);
        if (t == 0) wsf[1600] = out2_b[0];
    }
}

// One wave = 4 rows. Lane l = (row l>>4, sim-block l&15): loads its block's 64
// contiguous floats fully in-lane -> cosine needs ZERO cross-lane ops.
// MLP distributed: lane handles h = (l&15) and (l&15)+16 of its row.
// DS ops per wave: 16 (sim gather) + 32 (hid gather) + 4 (row reduce) = 52
// for 4 rows (13/row, was 101/row in R2).
__global__ __launch_bounds__(256) void stream_kernel(
    const float* __restrict__ inp1, const float* __restrict__ inp2,
    const float* __restrict__ wsf, float* __restrict__ out)
{
    const int tid = threadIdx.x;
    const int l   = tid & 63;
    const int W   = blockIdx.x * 4 + (tid >> 6);   // global wave id: rows 4W..4W+3
    const int p   = l & 15;                        // sim-block / h-index
    const int grp = l & 48;                        // row-group base lane

    // lane l covers floats [64l, 64l+64) of the wave's 4096-float slab
    const float4* p1 = reinterpret_cast<const float4*>(inp1) + ((size_t)W << 10) + (l << 4);
    const float4* p2 = reinterpret_cast<const float4*>(inp2) + ((size_t)W << 10) + (l << 4);

    float qq = 0.f, cc = 0.f, qc = 0.f;
    #pragma unroll
    for (int u = 0; u < 16; ++u) {
        float4 q = p1[u];
        float4 c = p2[u];
        qq = fmaf(q.w, q.w, fmaf(q.z, q.z, fmaf(q.y, q.y, fmaf(q.x, q.x, qq))));
        cc = fmaf(c.w, c.w, fmaf(c.z, c.z, fmaf(c.y, c.y, fmaf(c.x, c.x, cc))));
        qc = fmaf(q.w, c.w, fmaf(q.z, c.z, fmaf(q.y, c.y, fmaf(q.x, c.x, qc))));
    }
    // sim for (row = l>>4, block d = l&15)
    const float sim = qc / ((sqrtf(qq) + 1e-8f) * (sqrtf(cc) + 1e-8f));

    // ---- weight preloads (L1/L2-resident after the first waves per CU) ----
    float wA[16], wB[16];          // WsumT rows p, p+16
    {
        const float4* wsT = reinterpret_cast<const float4*>(wsf);
        #pragma unroll
        for (int j = 0; j < 4; ++j) {
            float4 a = wsT[p * 4 + j];
            float4 b = wsT[(p + 16) * 4 + j];
            wA[4*j+0]=a.x; wA[4*j+1]=a.y; wA[4*j+2]=a.z; wA[4*j+3]=a.w;
            wB[4*j+0]=b.x; wB[4*j+1]=b.y; wB[4*j+2]=b.z; wB[4*j+3]=b.w;
        }
    }
    float w1A[32], w1B[32];        // W1 rows p, p+16
    {
        const float4* w1p = reinterpret_cast<const float4*>(wsf + 512);
        #pragma unroll
        for (int j = 0; j < 8; ++j) {
            float4 a = w1p[p * 8 + j];
            float4 b = w1p[(p + 16) * 8 + j];
            w1A[4*j+0]=a.x; w1A[4*j+1]=a.y; w1A[4*j+2]=a.z; w1A[4*j+3]=a.w;
            w1B[4*j+0]=b.x; w1B[4*j+1]=b.y; w1B[4*j+2]=b.z; w1B[4*j+3]=b.w;
        }
    }
    const float b1A = wsf[1536 + p],      b1B = wsf[1536 + 16 + p];
    const float w2A = wsf[1568 + p],      w2B = wsf[1568 + 16 + p];
    const float b2  = wsf[1600];

    // ---- hid[row][h] for h = p, p+16 : gather own row's 16 sims (16 bpermutes) ----
    float hidA = 0.f, hidB = 0.f;
    #pragma unroll
    for (int d = 0; d < 16; ++d) {
        float s = __shfl(sim, grp | d, 64);
        hidA = fmaf(s, wA[d], hidA);
        hidB = fmaf(s, wB[d], hidB);
    }
    // ---- layer 2: a[h] = b1[h] + sum_j W1[h][j] hid[row][j] (32 bpermutes) ----
    float aA = b1A, aB = b1B;
    #pragma unroll
    for (int j = 0; j < 16; ++j) {
        float g = __shfl(hidA, grp | j, 64);          // hid[row][j]
        aA = fmaf(w1A[j], g, aA);
        aB = fmaf(w1B[j], g, aB);
    }
    #pragma unroll
    for (int j = 0; j < 16; ++j) {
        float g = __shfl(hidB, grp | j, 64);          // hid[row][16+j]
        aA = fmaf(w1A[16 + j], g, aA);
        aB = fmaf(w1B[16 + j], g, aB);
    }
    // ---- output: contrib per lane covers h = p and p+16; reduce over 16 lanes ----
    float contrib = fmaf(w2A, tanhf(aA), w2B * tanhf(aB));
    #pragma unroll
    for (int m = 1; m < 16; m <<= 1) contrib += __shfl_xor(contrib, m, 64);

    if (p == 0) {
        const unsigned r = (unsigned)(W * 4 + (l >> 4));
        atomicAdd(out + r / N_, (contrib + b2) * (1.f / (float)N_));
    }
}

extern "C" void kernel_launch(void* const* d_in, const int* in_sizes, int n_in,
                              void* d_out, int out_size, void* d_ws, size_t ws_size,
                              hipStream_t stream) {
    const float* inp1   = (const float*)d_in[0];
    const float* inp2   = (const float*)d_in[1];
    // d_in[2]=gk_mean, d_in[3]=gk_prec: provably irrelevant (see note above)
    const float* gcn_w  = (const float*)d_in[4];
    const float* out1_v = (const float*)d_in[5];
    const float* out1_g = (const float*)d_in[6];
    const float* out1_b = (const float*)d_in[7];
    const float* out2_v = (const float*)d_in[8];
    const float* out2_g = (const float*)d_in[9];
    const float* out2_b = (const float*)d_in[10];
    float* out = (float*)d_out;
    float* wsf = (float*)d_ws;

    hipMemsetAsync(out, 0, (size_t)out_size * sizeof(float), stream);
    fold_weights<<<1, 64, 0, stream>>>(gcn_w, out1_v, out1_g, out1_b,
                                       out2_v, out2_g, out2_b, wsf);
    stream_kernel<<<NROW / 16, 256, 0, stream>>>(inp1, inp2, wsf, out);
}